// Round 10
// baseline (3929.512 us; speedup 1.0000x reference)
//
#include <hip/hip_runtime.h>

#define BATCH 4
#define NPTS 8192
#define MPTS 2048
#define CIN 128
#define CO 256
#define KS 32
#define ND 32
#define HALF 128

typedef unsigned int u32;
typedef unsigned long long u64;

// DPP ctrl codes
#define DPPC_QUAD_XOR1 0xB1
#define DPPC_QUAD_XOR2 0x4E
#define DPPC_ROW_MIRROR 0x140
#define DPPC_ROW_HALF_MIRROR 0x141
#define DPPC_ROW_BCAST15 0x142
#define DPPC_ROW_BCAST31 0x143

template<int CTRL>
__device__ __forceinline__ float dpp_max(float v) {
    int o = __builtin_amdgcn_update_dpp(__float_as_int(-1e30f), __float_as_int(v),
                                        CTRL, 0xF, 0xF, false);
    return fmaxf(v, __int_as_float(o));
}
__device__ __forceinline__ float wave_max_f32(float v) {
    v = dpp_max<DPPC_QUAD_XOR1>(v);
    v = dpp_max<DPPC_QUAD_XOR2>(v);
    v = dpp_max<DPPC_ROW_HALF_MIRROR>(v);
    v = dpp_max<DPPC_ROW_MIRROR>(v);
    v = dpp_max<DPPC_ROW_BCAST15>(v);
    v = dpp_max<DPPC_ROW_BCAST31>(v);
    return __int_as_float(__builtin_amdgcn_readlane(__float_as_int(v), 63));
}

// ---------------- FPS v5: real register residency for per-thread state ---------
// __launch_bounds__(512, 2): only 4 blocks run chip-wide; declare low occupancy
// so the backend budgets up to 256 VGPRs/wave instead of 48 (R9: pin without
// budget => scratch spill, 3533 us).
__global__ __launch_bounds__(512, 2) void k_fps(const float* __restrict__ p,
                                                float* __restrict__ out_newp,
                                                int* __restrict__ idx) {
    __shared__ u64 wkey[2][8];
    __shared__ float wcx[2][8], wcy[2][8], wcz[2][8];
    __shared__ float obuf[MPTS * 3];   // 24 KB
    __shared__ int   oidx[MPTS];       // 8 KB
    int b = blockIdx.x, t = threadIdx.x;
    int lane = t & 63, wid = t >> 6;
    const float* pb = p + (size_t)b * NPTS * 3;
    float x[16], y[16], z[16], dist[16];
    int j0 = t * 16;
#pragma unroll
    for (int i = 0; i < 16; ++i) {
        x[i] = pb[(j0 + i) * 3 + 0];
        y[i] = pb[(j0 + i) * 3 + 1];
        z[i] = pb[(j0 + i) * 3 + 2];
        dist[i] = 1e10f;
    }
#pragma unroll
    for (int i = 0; i < 16; ++i) {     // pin: forbid re-load rematerialization
        asm volatile("" : "+v"(x[i]), "+v"(y[i]), "+v"(z[i]));
    }
    float lx = pb[0], ly = pb[1], lz = pb[2];
    if (t == 0) { obuf[0] = lx; obuf[1] = ly; obuf[2] = lz; oidx[0] = 0; }
    for (int s = 1; s < MPTS; ++s) {
        int par = s & 1;
        float bv = -1e30f; int bi = 0;
#pragma unroll
        for (int i = 0; i < 16; ++i) {
            // numpy-f32 order: (dx*dx + dy*dy) + dz*dz, no FMA contraction
            float dx = __fsub_rn(x[i], lx);
            float dy = __fsub_rn(y[i], ly);
            float dz = __fsub_rn(z[i], lz);
            float d  = __fadd_rn(__fadd_rn(__fmul_rn(dx, dx), __fmul_rn(dy, dy)),
                                 __fmul_rn(dz, dz));
            float nd = fminf(dist[i], d);
            dist[i] = nd;
            bool gt = nd > bv;          // strict > keeps lowest local index
            bi = gt ? i : bi;
            bv = fmaxf(bv, nd);
        }
        float gmw = wave_max_f32(bv);
        u64 mask = __ballot(bv == gmw);
        int first = __ffsll((long long)mask) - 1;
        if (lane == first) {            // wave winner: extract candidate coords
            float sx = x[0], sy = y[0], sz = z[0];
#pragma unroll
            for (int k = 1; k < 16; ++k) {
                if (bi == k) { sx = x[k]; sy = y[k]; sz = z[k]; }
            }
            wkey[par][wid] = ((u64)__float_as_uint(gmw) << 32)
                           | (u64)(u32)(NPTS - 1 - (j0 + bi));
            wcx[par][wid] = sx; wcy[par][wid] = sy; wcz[par][wid] = sz;
        }
        __syncthreads();                // only barrier; no vmem in flight
        u64 bestk = wkey[par][0]; int bw = 0;
#pragma unroll
        for (int ww = 1; ww < 8; ++ww) {
            u64 kk = wkey[par][ww];
            if (kk > bestk) { bestk = kk; bw = ww; }
        }
        int w0 = (NPTS - 1 - (int)(bestk & 0xFFFFFFFFull)) & (NPTS - 1);
        lx = wcx[par][bw]; ly = wcy[par][bw]; lz = wcz[par][bw];
        if (t == 0) {
            oidx[s] = w0;
            obuf[s * 3 + 0] = lx; obuf[s * 3 + 1] = ly; obuf[s * 3 + 2] = lz;
        }
        // parity double-buffer: next same-parity write happens only after the
        // next barrier, which is after all reads here -> no second barrier.
    }
    __syncthreads();
    for (int e = t; e < MPTS * 3; e += 512) out_newp[(size_t)b * MPTS * 3 + e] = obuf[e];
    for (int e = t; e < MPTS; e += 512)     idx[b * MPTS + e] = oidx[e];
}

// ---------------- f1[bl][n][c] = conv1_w @ f[b] + bias (f32, n-major) ----------
__global__ __launch_bounds__(256) void k_f1(const float* __restrict__ f,
                                            const float* __restrict__ conv1_w,
                                            const float* __restrict__ conv1_b,
                                            float* __restrict__ f1t, int b0) {
    __shared__ __align__(16) float fT[CIN * 16];   // [k][j]
    int blk = blockIdx.x;
    int bl = blk >> 9;
    int b = b0 + bl;
    int n0 = (blk & 511) << 4;
    int t = threadIdx.x;
    const float* fb = f + (size_t)b * CIN * NPTS;
    for (int e = t; e < CIN * 16; e += 256) {
        int k = e >> 4, j = e & 15;
        fT[e] = fb[(size_t)k * NPTS + n0 + j];
    }
    __syncthreads();
    int c = t;
    float bias = conv1_b[c];
    float acc[16];
#pragma unroll
    for (int j = 0; j < 16; ++j) acc[j] = bias;
    const float4* wrow4 = (const float4*)(conv1_w + (size_t)c * CIN);
    const float4* fT4 = (const float4*)fT;
    for (int k4 = 0; k4 < 32; ++k4) {
        float4 wv = wrow4[k4];
#pragma unroll
        for (int sub = 0; sub < 4; ++sub) {
            float w = sub == 0 ? wv.x : sub == 1 ? wv.y : sub == 2 ? wv.z : wv.w;
            int k = k4 * 4 + sub;
            float4 a0 = fT4[k*4+0], a1 = fT4[k*4+1], a2 = fT4[k*4+2], a3 = fT4[k*4+3];
            acc[0]  = fmaf(w, a0.x, acc[0]);  acc[1]  = fmaf(w, a0.y, acc[1]);
            acc[2]  = fmaf(w, a0.z, acc[2]);  acc[3]  = fmaf(w, a0.w, acc[3]);
            acc[4]  = fmaf(w, a1.x, acc[4]);  acc[5]  = fmaf(w, a1.y, acc[5]);
            acc[6]  = fmaf(w, a1.z, acc[6]);  acc[7]  = fmaf(w, a1.w, acc[7]);
            acc[8]  = fmaf(w, a2.x, acc[8]);  acc[9]  = fmaf(w, a2.y, acc[9]);
            acc[10] = fmaf(w, a2.z, acc[10]); acc[11] = fmaf(w, a2.w, acc[11]);
            acc[12] = fmaf(w, a3.x, acc[12]); acc[13] = fmaf(w, a3.y, acc[13]);
            acc[14] = fmaf(w, a3.z, acc[14]); acc[15] = fmaf(w, a3.w, acc[15]);
        }
    }
    float* dst = f1t + ((size_t)bl * NPTS + n0) * CO + c;
#pragma unroll
    for (int j = 0; j < 16; ++j) dst[(size_t)j * CO] = acc[j];
}

// ------- per-query kernel, light: ball query + tmax + f1-gather max + MLPs -----
__global__ __launch_bounds__(256) void k_feat(
    const float* __restrict__ p, const float* __restrict__ f,
    const float* __restrict__ f1t,
    const float* __restrict__ skip_w,  const float* __restrict__ skip_b,
    const float* __restrict__ bn1_g, const float* __restrict__ bn1_b,
    const float* __restrict__ bn1_m, const float* __restrict__ bn1_v,
    const float* __restrict__ dirv,  const float* __restrict__ de_w1,
    const float* __restrict__ de_g,  const float* __restrict__ de_bb,
    const float* __restrict__ de_m,  const float* __restrict__ de_v,
    const float* __restrict__ de_w2, const float* __restrict__ de_b2,
    const int* __restrict__ idx,     float* __restrict__ out_f, int b0) {
    __shared__ float sdx[KS], sdy[KS], sdz[KS];
    __shared__ float ltm[ND], lfi[CIN], lh[HALF];
    __shared__ int swidx[4][KS];
    __shared__ int scnt[4];
    __shared__ int nb[KS], nbp[KS];

    int q = b0 * MPTS + blockIdx.x;
    int b = q >> 11;
    int bl = b - b0;
    int m = q & (MPTS - 1);
    int t = threadIdx.x, lane = t & 63, w = t >> 6;
    const float* pb = p + (size_t)b * NPTS * 3;
    int i0 = idx[q] & (NPTS - 1);
    float qx = pb[i0 * 3 + 0], qy = pb[i0 * 3 + 1], qz = pb[i0 * 3 + 2];
    const float R2 = 0.1f * 0.1f;

    int cnt = 0;
    int seg = w * 2048;
    for (int base = 0; base < 2048; base += 64) {
        int j = seg + base + lane;
        float dx = __fsub_rn(pb[j * 3 + 0], qx);
        float dy = __fsub_rn(pb[j * 3 + 1], qy);
        float dz = __fsub_rn(pb[j * 3 + 2], qz);
        float d2 = __fadd_rn(__fadd_rn(__fmul_rn(dx, dx), __fmul_rn(dy, dy)),
                             __fmul_rn(dz, dz));
        bool hit = d2 < R2;
        u64 mask = __ballot(hit);
        if (hit) {
            int pos = cnt + __popcll(mask & ((1ull << lane) - 1ull));
            if (pos < KS) swidx[w][pos] = j;
        }
        cnt += __popcll(mask);
        if (cnt >= KS) break;
    }
    if (lane == 0) scnt[w] = cnt < KS ? cnt : KS;
    __syncthreads();
    int c0s = scnt[0], c1s = scnt[1], c2s = scnt[2], c3s = scnt[3];
    int st1 = c0s, st2 = c0s + c1s, st3 = c0s + c1s + c2s;
    int total = c0s + c1s + c2s + c3s; if (total > KS) total = KS;
    if (total < 1) total = 1;
    if (t < 128) {
        int ww = t >> 5, l = t & 31;
        int stw = (ww == 0) ? 0 : (ww == 1) ? st1 : (ww == 2) ? st2 : st3;
        int cw  = (ww == 0) ? c0s : (ww == 1) ? c1s : (ww == 2) ? c2s : c3s;
        int gp = stw + l;
        if (l < cw && gp < KS) nb[gp] = swidx[ww][l];
    }
    __syncthreads();
    if (t < KS) {
        int jk = nb[t < total ? t : 0] & (NPTS - 1);
        nbp[t] = jk;
        float dx = pb[jk * 3 + 0] - qx;
        float dy = pb[jk * 3 + 1] - qy;
        float dz = pb[jk * 3 + 2] - qz;
        float nr = fmaxf(sqrtf(dx * dx + dy * dy + dz * dz), 1e-12f);
        sdx[t] = dx / nr; sdy[t] = dy / nr; sdz[t] = dz / nr;
    }
    if (t >= 128) {
        lfi[t - 128] = f[((size_t)b * CIN + (t - 128)) * NPTS + i0];
    }
    __syncthreads();
    if (t < ND) {
        float ax = dirv[t * 3], ay = dirv[t * 3 + 1], az = dirv[t * 3 + 2];
        float n = fmaxf(sqrtf(ax * ax + ay * ay + az * az), 1e-12f);
        float vx = ax / n, vy = ay / n, vz = az / n;
        float tm = -1e30f;
#pragma unroll
        for (int k = 0; k < KS; ++k)
            tm = fmaxf(tm, vx * sdx[k] + vy * sdy[k] + vz * sdz[k]);
        ltm[t] = tm;
    }
    __syncthreads();

    int c = t;
    const float* f1b = f1t + (size_t)bl * NPTS * CO + c;
    float mx = -1e30f;
#pragma unroll 8
    for (int k = 0; k < KS; ++k) {
        mx = fmaxf(mx, f1b[(size_t)nbp[k] * CO]);
    }
    float sc1 = bn1_g[c] / sqrtf(bn1_v[c] + 1e-5f);
    float o1 = (mx - bn1_m[c]) * sc1 + bn1_b[c];

    float idv = skip_b[c];
    {
        const float4* sr = (const float4*)(skip_w + (size_t)c * CIN);
#pragma unroll 8
        for (int r = 0; r < 32; ++r) {
            float4 v = sr[r];
            idv = fmaf(v.x, lfi[r*4+0], fmaf(v.y, lfi[r*4+1],
                  fmaf(v.z, lfi[r*4+2], fmaf(v.w, lfi[r*4+3], idv))));
        }
    }
    {
        int hc = c & (HALF - 1);
        const float4* d1 = (const float4*)(de_w1 + (size_t)hc * ND);
        float a = 0.0f;
#pragma unroll
        for (int r = 0; r < 8; ++r) {
            float4 v = d1[r];
            a = fmaf(v.x, ltm[r*4+0], fmaf(v.y, ltm[r*4+1],
                fmaf(v.z, ltm[r*4+2], fmaf(v.w, ltm[r*4+3], a))));
        }
        float dsc = de_g[hc] / sqrtf(de_v[hc] + 1e-5f);
        float xb = (a - de_m[hc]) * dsc + de_bb[hc];
        float hv = 0.5f * xb * (1.0f + erff(xb * 0.70710678118654752440f));
        if (c < HALF) lh[c] = hv;
    }
    __syncthreads();
    float pe = de_b2[c];
    {
        const float4* d2p = (const float4*)(de_w2 + (size_t)c * HALF);
#pragma unroll 8
        for (int r = 0; r < 32; ++r) {
            float4 v = d2p[r];
            pe = fmaf(v.x, lh[r*4+0], fmaf(v.y, lh[r*4+1],
                 fmaf(v.z, lh[r*4+2], fmaf(v.w, lh[r*4+3], pe))));
        }
    }
    out_f[((size_t)b * CO + c) * MPTS + m] = o1 + pe + idv;
}

// ------------- fused fallback if ws too small ----------------------------------
__global__ __launch_bounds__(256) void k_featz_fused(
    const float* __restrict__ p, const float* __restrict__ f,
    const float* __restrict__ conv1_w, const float* __restrict__ conv1_b,
    const float* __restrict__ skip_w,  const float* __restrict__ skip_b,
    const float* __restrict__ bn1_g, const float* __restrict__ bn1_b,
    const float* __restrict__ bn1_m, const float* __restrict__ bn1_v,
    const float* __restrict__ dirv,  const float* __restrict__ de_w1,
    const float* __restrict__ de_g,  const float* __restrict__ de_bb,
    const float* __restrict__ de_m,  const float* __restrict__ de_v,
    const float* __restrict__ de_w2, const float* __restrict__ de_b2,
    const int* __restrict__ idx,     float* __restrict__ out_f) {
    __shared__ __align__(16) float fg[KS * CIN];
    __shared__ float sdx[KS], sdy[KS], sdz[KS];
    __shared__ float ltm[ND], lfi[CIN], lh[HALF];
    __shared__ int swidx[4][KS];
    __shared__ int scnt[4];
    __shared__ int nb[KS], nbp[KS];

    int q = blockIdx.x;
    int b = q >> 11;
    int m = q & (MPTS - 1);
    int t = threadIdx.x, lane = t & 63, w = t >> 6;
    const float* pb = p + (size_t)b * NPTS * 3;
    int i0 = idx[q] & (NPTS - 1);
    float qx = pb[i0 * 3 + 0], qy = pb[i0 * 3 + 1], qz = pb[i0 * 3 + 2];
    const float R2 = 0.1f * 0.1f;
    int cnt = 0;
    int seg = w * 2048;
    for (int base = 0; base < 2048; base += 64) {
        int j = seg + base + lane;
        float dx = __fsub_rn(pb[j * 3 + 0], qx);
        float dy = __fsub_rn(pb[j * 3 + 1], qy);
        float dz = __fsub_rn(pb[j * 3 + 2], qz);
        float d2 = __fadd_rn(__fadd_rn(__fmul_rn(dx, dx), __fmul_rn(dy, dy)),
                             __fmul_rn(dz, dz));
        bool hit = d2 < R2;
        u64 mask = __ballot(hit);
        if (hit) {
            int pos = cnt + __popcll(mask & ((1ull << lane) - 1ull));
            if (pos < KS) swidx[w][pos] = j;
        }
        cnt += __popcll(mask);
        if (cnt >= KS) break;
    }
    if (lane == 0) scnt[w] = cnt < KS ? cnt : KS;
    __syncthreads();
    int c0s = scnt[0], c1s = scnt[1], c2s = scnt[2], c3s = scnt[3];
    int st1 = c0s, st2 = c0s + c1s, st3 = c0s + c1s + c2s;
    int total = c0s + c1s + c2s + c3s; if (total > KS) total = KS;
    if (total < 1) total = 1;
    if (t < 128) {
        int ww = t >> 5, l = t & 31;
        int stw = (ww == 0) ? 0 : (ww == 1) ? st1 : (ww == 2) ? st2 : st3;
        int cw  = (ww == 0) ? c0s : (ww == 1) ? c1s : (ww == 2) ? c2s : c3s;
        int gp = stw + l;
        if (l < cw && gp < KS) nb[gp] = swidx[ww][l];
    }
    __syncthreads();
    if (t < KS) {
        int jk = nb[t < total ? t : 0] & (NPTS - 1);
        nbp[t] = jk;
        float dx = pb[jk * 3 + 0] - qx;
        float dy = pb[jk * 3 + 1] - qy;
        float dz = pb[jk * 3 + 2] - qz;
        float nr = fmaxf(sqrtf(dx * dx + dy * dy + dz * dz), 1e-12f);
        sdx[t] = dx / nr; sdy[t] = dy / nr; sdz[t] = dz / nr;
    }
    if (t >= 128) lfi[t - 128] = f[((size_t)b * CIN + (t - 128)) * NPTS + i0];
    __syncthreads();
    if (t < ND) {
        float ax = dirv[t * 3], ay = dirv[t * 3 + 1], az = dirv[t * 3 + 2];
        float n = fmaxf(sqrtf(ax * ax + ay * ay + az * az), 1e-12f);
        float vx = ax / n, vy = ay / n, vz = az / n;
        float tm = -1e30f;
#pragma unroll
        for (int k = 0; k < KS; ++k)
            tm = fmaxf(tm, vx * sdx[k] + vy * sdy[k] + vz * sdz[k]);
        ltm[t] = tm;
    }
    for (int e = t; e < KS * CIN; e += 256) {
        int k = e >> 7, i = e & 127;
        fg[k * CIN + i] = f[((size_t)b * CIN + i) * NPTS + nbp[k]];
    }
    __syncthreads();
    int c = t;
    float acc[KS];
#pragma unroll
    for (int k = 0; k < KS; ++k) acc[k] = 0.0f;
    const float4* w4 = (const float4*)(conv1_w + (size_t)c * CIN);
    const float4* fg4 = (const float4*)fg;
    for (int i4 = 0; i4 < 32; ++i4) {
        float4 wv = w4[i4];
#pragma unroll 8
        for (int k = 0; k < KS; ++k) {
            float4 g = fg4[k * 32 + i4];
            acc[k] = fmaf(wv.x, g.x, fmaf(wv.y, g.y,
                     fmaf(wv.z, g.z, fmaf(wv.w, g.w, acc[k]))));
        }
    }
    float bias = conv1_b[c];
    float mx = -1e30f;
#pragma unroll
    for (int k = 0; k < KS; ++k) mx = fmaxf(mx, acc[k] + bias);
    float sc1 = bn1_g[c] / sqrtf(bn1_v[c] + 1e-5f);
    float o1 = (mx - bn1_m[c]) * sc1 + bn1_b[c];
    float idv = skip_b[c];
    {
        const float4* sr = (const float4*)(skip_w + (size_t)c * CIN);
#pragma unroll 8
        for (int r = 0; r < 32; ++r) {
            float4 v = sr[r];
            idv = fmaf(v.x, lfi[r*4+0], fmaf(v.y, lfi[r*4+1],
                  fmaf(v.z, lfi[r*4+2], fmaf(v.w, lfi[r*4+3], idv))));
        }
    }
    {
        int hc = c & (HALF - 1);
        const float4* d1 = (const float4*)(de_w1 + (size_t)hc * ND);
        float a = 0.0f;
#pragma unroll
        for (int r = 0; r < 8; ++r) {
            float4 v = d1[r];
            a = fmaf(v.x, ltm[r*4+0], fmaf(v.y, ltm[r*4+1],
                fmaf(v.z, ltm[r*4+2], fmaf(v.w, ltm[r*4+3], a))));
        }
        float dsc = de_g[hc] / sqrtf(de_v[hc] + 1e-5f);
        float xb = (a - de_m[hc]) * dsc + de_bb[hc];
        float hv = 0.5f * xb * (1.0f + erff(xb * 0.70710678118654752440f));
        if (c < HALF) lh[c] = hv;
    }
    __syncthreads();
    float pe = de_b2[c];
    {
        const float4* d2p = (const float4*)(de_w2 + (size_t)c * HALF);
#pragma unroll 8
        for (int r = 0; r < 32; ++r) {
            float4 v = d2p[r];
            pe = fmaf(v.x, lh[r*4+0], fmaf(v.y, lh[r*4+1],
                 fmaf(v.z, lh[r*4+2], fmaf(v.w, lh[r*4+3], pe))));
        }
    }
    out_f[((size_t)b * CO + c) * MPTS + m] = o1 + pe + idv;
}

extern "C" void kernel_launch(void* const* d_in, const int* in_sizes, int n_in,
                              void* d_out, int out_size, void* d_ws, size_t ws_size,
                              hipStream_t stream) {
    const float* p       = (const float*)d_in[0];
    const float* f       = (const float*)d_in[1];
    const float* conv1_w = (const float*)d_in[2];
    const float* conv1_b = (const float*)d_in[3];
    const float* skip_w  = (const float*)d_in[4];
    const float* skip_b  = (const float*)d_in[5];
    const float* bn1_g   = (const float*)d_in[6];
    const float* bn1_b   = (const float*)d_in[7];
    const float* bn1_m   = (const float*)d_in[8];
    const float* bn1_v   = (const float*)d_in[9];
    const float* dirv    = (const float*)d_in[10];
    const float* de_w1   = (const float*)d_in[11];
    const float* de_g    = (const float*)d_in[12];
    const float* de_bb   = (const float*)d_in[13];
    const float* de_m    = (const float*)d_in[14];
    const float* de_v    = (const float*)d_in[15];
    const float* de_w2   = (const float*)d_in[16];
    const float* de_b2   = (const float*)d_in[17];

    float* out_newp = (float*)d_out;
    float* out_f    = (float*)d_out + (size_t)BATCH * MPTS * 3;
    int*   idx      = (int*)d_ws;                         // 32 KB
    float* f1t      = (float*)((char*)d_ws + 32768);

    size_t f1_one  = (size_t)NPTS * CO * 4;               // 8 MB per batch
    size_t need_full = 32768 + 4 * f1_one;
    size_t need_one  = 32768 + f1_one;
    int mode = (ws_size >= need_full) ? 2 : (ws_size >= need_one) ? 1 : 0;

    k_fps<<<dim3(BATCH), dim3(512), 0, stream>>>(p, out_newp, idx);

    if (mode == 2) {
        k_f1  <<<dim3(4 * 512),  dim3(256), 0, stream>>>(f, conv1_w, conv1_b, f1t, 0);
        k_feat<<<dim3(4 * MPTS), dim3(256), 0, stream>>>(
            p, f, f1t, skip_w, skip_b, bn1_g, bn1_b, bn1_m, bn1_v,
            dirv, de_w1, de_g, de_bb, de_m, de_v, de_w2, de_b2, idx, out_f, 0);
    } else if (mode == 1) {
        for (int b0 = 0; b0 < BATCH; ++b0) {
            k_f1  <<<dim3(512),  dim3(256), 0, stream>>>(f, conv1_w, conv1_b, f1t, b0);
            k_feat<<<dim3(MPTS), dim3(256), 0, stream>>>(
                p, f, f1t, skip_w, skip_b, bn1_g, bn1_b, bn1_m, bn1_v,
                dirv, de_w1, de_g, de_bb, de_m, de_v, de_w2, de_b2, idx, out_f, b0);
        }
    } else {
        k_featz_fused<<<dim3(BATCH * MPTS), dim3(256), 0, stream>>>(
            p, f, conv1_w, conv1_b, skip_w, skip_b, bn1_g, bn1_b, bn1_m, bn1_v,
            dirv, de_w1, de_g, de_bb, de_m, de_v, de_w2, de_b2, idx, out_f);
    }
}

// Round 11
// 2814.462 us; speedup vs baseline: 1.3962x; 1.3962x over previous
//
#include <hip/hip_runtime.h>

#define BATCH 4
#define NPTS 8192
#define MPTS 2048
#define CIN 128
#define CO 256
#define KS 32
#define ND 32
#define HALF 128

typedef unsigned int u32;
typedef unsigned long long u64;

// DPP ctrl codes
#define DPPC_QUAD_XOR1 0xB1
#define DPPC_QUAD_XOR2 0x4E
#define DPPC_ROW_MIRROR 0x140
#define DPPC_ROW_HALF_MIRROR 0x141
#define DPPC_ROW_BCAST15 0x142
#define DPPC_ROW_BCAST31 0x143

template<int CTRL>
__device__ __forceinline__ float dpp_max(float v) {
    int o = __builtin_amdgcn_update_dpp(__float_as_int(-1e30f), __float_as_int(v),
                                        CTRL, 0xF, 0xF, false);
    return fmaxf(v, __int_as_float(o));
}
__device__ __forceinline__ float wave_max_f32(float v) {
    v = dpp_max<DPPC_QUAD_XOR1>(v);
    v = dpp_max<DPPC_QUAD_XOR2>(v);
    v = dpp_max<DPPC_ROW_HALF_MIRROR>(v);
    v = dpp_max<DPPC_ROW_MIRROR>(v);
    v = dpp_max<DPPC_ROW_BCAST15>(v);
    v = dpp_max<DPPC_ROW_BCAST31>(v);
    return __int_as_float(__builtin_amdgcn_readlane(__float_as_int(v), 63));
}

// ------- FPS (blocks 0..3) fused with conv1 f1 precompute (blocks 4..1027) -----
// FPS: R8's proven structure; coords re-read per step as 12 aligned dwordx4
// chunks (explicit, instead of compiler's ~48 scalar remat loads). dist[16]
// stays in registers (fits the 48-VGPR allocation R8 demonstrated).
// f1 blocks run on the other 252 CUs, fully hidden under the serial FPS.
__global__ __launch_bounds__(512) void k_fps_f1(
    const float* __restrict__ p, const float* __restrict__ f,
    const float* __restrict__ conv1_w, const float* __restrict__ conv1_b,
    float* __restrict__ out_newp, int* __restrict__ idx,
    float* __restrict__ f1t) {
    if (blockIdx.x < 4) {
        __shared__ u64 wkey[2][8];
        int b = blockIdx.x, t = threadIdx.x;
        int lane = t & 63, wid = t >> 6;
        int j0 = t * 16;
        const float* pb = p + (size_t)b * NPTS * 3;
        const float* pt = pb + t * 48;         // this thread's 16 points (48 floats)
        float dist[16];
#pragma unroll
        for (int i = 0; i < 16; ++i) dist[i] = 1e10f;
        float lx = pb[0], ly = pb[1], lz = pb[2];
        if (t == 0) {
            out_newp[(size_t)b * MPTS * 3 + 0] = lx;
            out_newp[(size_t)b * MPTS * 3 + 1] = ly;
            out_newp[(size_t)b * MPTS * 3 + 2] = lz;
            idx[b * MPTS] = 0;
        }
        for (int s = 1; s < MPTS; ++s) {
            int par = s & 1;
            float bv = -1e30f; int bi = 0;
#pragma unroll
            for (int c = 0; c < 4; ++c) {
                float4 q0 = *(const float4*)(pt + c * 12 + 0);
                float4 q1 = *(const float4*)(pt + c * 12 + 4);
                float4 q2 = *(const float4*)(pt + c * 12 + 8);
                float cx[4] = { q0.x, q0.w, q1.z, q2.y };
                float cy[4] = { q0.y, q1.x, q1.w, q2.z };
                float cz[4] = { q0.z, q1.y, q2.x, q2.w };
#pragma unroll
                for (int i = 0; i < 4; ++i) {
                    // numpy-f32 order: (dx*dx + dy*dy) + dz*dz, no FMA contraction
                    float dx = __fsub_rn(cx[i], lx);
                    float dy = __fsub_rn(cy[i], ly);
                    float dz = __fsub_rn(cz[i], lz);
                    float d  = __fadd_rn(__fadd_rn(__fmul_rn(dx, dx), __fmul_rn(dy, dy)),
                                         __fmul_rn(dz, dz));
                    int li = c * 4 + i;
                    float nd = fminf(dist[li], d);
                    dist[li] = nd;
                    bool gt = nd > bv;          // strict > keeps lowest local index
                    bi = gt ? li : bi;
                    bv = fmaxf(bv, nd);
                }
            }
            float gmw = wave_max_f32(bv);
            u64 mask = __ballot(bv == gmw);
            int first = __ffsll((long long)mask) - 1;
            if (lane == first) {
                wkey[par][wid] = ((u64)__float_as_uint(gmw) << 32)
                               | (u64)(u32)(NPTS - 1 - (j0 + bi));
            }
            __syncthreads();                    // only barrier per step
            u64 bestk = wkey[par][0];
#pragma unroll
            for (int ww = 1; ww < 8; ++ww) {
                u64 kk = wkey[par][ww];
                if (kk > bestk) bestk = kk;
            }
            int w0 = (NPTS - 1 - (int)(bestk & 0xFFFFFFFFull)) & (NPTS - 1);
            lx = pb[w0 * 3 + 0]; ly = pb[w0 * 3 + 1]; lz = pb[w0 * 3 + 2];
            if (t == 0) {
                idx[b * MPTS + s] = w0;
                out_newp[((size_t)b * MPTS + s) * 3 + 0] = lx;
                out_newp[((size_t)b * MPTS + s) * 3 + 1] = ly;
                out_newp[((size_t)b * MPTS + s) * 3 + 2] = lz;
            }
            // parity double-buffer: next same-parity write happens only after
            // the next barrier, i.e. after all reads here -> no second barrier.
        }
    } else if (f1t != nullptr) {
        // f1[b][n][c] = conv1_w @ f[b] + bias; 32 points per block, 512 threads
        __shared__ __align__(16) float fT[CIN * 32];   // [k][j], 16 KB
        int blk = blockIdx.x - 4;              // 0..1023
        int b = blk >> 8;
        int n0 = (blk & 255) << 5;
        int t = threadIdx.x;
        const float* fb = f + (size_t)b * CIN * NPTS;
        for (int e = t; e < CIN * 32; e += 512) {
            int k = e >> 5, j = e & 31;
            fT[e] = fb[(size_t)k * NPTS + n0 + j];
        }
        __syncthreads();
        int c = t & 255, jh = (t >> 8) << 4;   // half: j in [jh, jh+16)
        float bias = conv1_b[c];
        float acc[16];
#pragma unroll
        for (int j = 0; j < 16; ++j) acc[j] = bias;
        const float4* wrow4 = (const float4*)(conv1_w + (size_t)c * CIN);
        const float4* fT4 = (const float4*)fT;
        for (int k4 = 0; k4 < 32; ++k4) {
            float4 wv = wrow4[k4];
#pragma unroll
            for (int sub = 0; sub < 4; ++sub) {
                float w = sub == 0 ? wv.x : sub == 1 ? wv.y : sub == 2 ? wv.z : wv.w;
                int k = k4 * 4 + sub;
                int base = (k * 32 + jh) >> 2;
                float4 a0 = fT4[base+0], a1 = fT4[base+1], a2 = fT4[base+2], a3 = fT4[base+3];
                acc[0]  = fmaf(w, a0.x, acc[0]);  acc[1]  = fmaf(w, a0.y, acc[1]);
                acc[2]  = fmaf(w, a0.z, acc[2]);  acc[3]  = fmaf(w, a0.w, acc[3]);
                acc[4]  = fmaf(w, a1.x, acc[4]);  acc[5]  = fmaf(w, a1.y, acc[5]);
                acc[6]  = fmaf(w, a1.z, acc[6]);  acc[7]  = fmaf(w, a1.w, acc[7]);
                acc[8]  = fmaf(w, a2.x, acc[8]);  acc[9]  = fmaf(w, a2.y, acc[9]);
                acc[10] = fmaf(w, a2.z, acc[10]); acc[11] = fmaf(w, a2.w, acc[11]);
                acc[12] = fmaf(w, a3.x, acc[12]); acc[13] = fmaf(w, a3.y, acc[13]);
                acc[14] = fmaf(w, a3.z, acc[14]); acc[15] = fmaf(w, a3.w, acc[15]);
            }
        }
        float* dst = f1t + ((size_t)b * NPTS + n0 + jh) * CO + c;
#pragma unroll
        for (int j = 0; j < 16; ++j) dst[(size_t)j * CO] = acc[j];
    }
}

// ---------------- standalone f1 (mode 1 per-batch fallback) --------------------
__global__ __launch_bounds__(256) void k_f1(const float* __restrict__ f,
                                            const float* __restrict__ conv1_w,
                                            const float* __restrict__ conv1_b,
                                            float* __restrict__ f1t, int b0) {
    __shared__ __align__(16) float fT[CIN * 16];
    int blk = blockIdx.x;
    int bl = blk >> 9;
    int b = b0 + bl;
    int n0 = (blk & 511) << 4;
    int t = threadIdx.x;
    const float* fb = f + (size_t)b * CIN * NPTS;
    for (int e = t; e < CIN * 16; e += 256) {
        int k = e >> 4, j = e & 15;
        fT[e] = fb[(size_t)k * NPTS + n0 + j];
    }
    __syncthreads();
    int c = t;
    float bias = conv1_b[c];
    float acc[16];
#pragma unroll
    for (int j = 0; j < 16; ++j) acc[j] = bias;
    const float4* wrow4 = (const float4*)(conv1_w + (size_t)c * CIN);
    const float4* fT4 = (const float4*)fT;
    for (int k4 = 0; k4 < 32; ++k4) {
        float4 wv = wrow4[k4];
#pragma unroll
        for (int sub = 0; sub < 4; ++sub) {
            float w = sub == 0 ? wv.x : sub == 1 ? wv.y : sub == 2 ? wv.z : wv.w;
            int k = k4 * 4 + sub;
            float4 a0 = fT4[k*4+0], a1 = fT4[k*4+1], a2 = fT4[k*4+2], a3 = fT4[k*4+3];
            acc[0]  = fmaf(w, a0.x, acc[0]);  acc[1]  = fmaf(w, a0.y, acc[1]);
            acc[2]  = fmaf(w, a0.z, acc[2]);  acc[3]  = fmaf(w, a0.w, acc[3]);
            acc[4]  = fmaf(w, a1.x, acc[4]);  acc[5]  = fmaf(w, a1.y, acc[5]);
            acc[6]  = fmaf(w, a1.z, acc[6]);  acc[7]  = fmaf(w, a1.w, acc[7]);
            acc[8]  = fmaf(w, a2.x, acc[8]);  acc[9]  = fmaf(w, a2.y, acc[9]);
            acc[10] = fmaf(w, a2.z, acc[10]); acc[11] = fmaf(w, a2.w, acc[11]);
            acc[12] = fmaf(w, a3.x, acc[12]); acc[13] = fmaf(w, a3.y, acc[13]);
            acc[14] = fmaf(w, a3.z, acc[14]); acc[15] = fmaf(w, a3.w, acc[15]);
        }
    }
    float* dst = f1t + ((size_t)bl * NPTS + n0) * CO + c;
#pragma unroll
    for (int j = 0; j < 16; ++j) dst[(size_t)j * CO] = acc[j];
}

// ------- per-query kernel: ball query + tmax + f1-gather max + MLPs ------------
__global__ __launch_bounds__(256) void k_feat(
    const float* __restrict__ p, const float* __restrict__ f,
    const float* __restrict__ f1t,
    const float* __restrict__ skip_w,  const float* __restrict__ skip_b,
    const float* __restrict__ bn1_g, const float* __restrict__ bn1_b,
    const float* __restrict__ bn1_m, const float* __restrict__ bn1_v,
    const float* __restrict__ dirv,  const float* __restrict__ de_w1,
    const float* __restrict__ de_g,  const float* __restrict__ de_bb,
    const float* __restrict__ de_m,  const float* __restrict__ de_v,
    const float* __restrict__ de_w2, const float* __restrict__ de_b2,
    const int* __restrict__ idx,     float* __restrict__ out_f, int b0) {
    __shared__ float sdx[KS], sdy[KS], sdz[KS];
    __shared__ float ltm[ND], lfi[CIN], lh[HALF];
    __shared__ int swidx[4][KS];
    __shared__ int scnt[4];
    __shared__ int nb[KS], nbp[KS];

    int q = b0 * MPTS + blockIdx.x;
    int b = q >> 11;
    int bl = b - b0;
    int m = q & (MPTS - 1);
    int t = threadIdx.x, lane = t & 63, w = t >> 6;
    const float* pb = p + (size_t)b * NPTS * 3;
    int i0 = idx[q] & (NPTS - 1);
    float qx = pb[i0 * 3 + 0], qy = pb[i0 * 3 + 1], qz = pb[i0 * 3 + 2];
    const float R2 = 0.1f * 0.1f;

    int cnt = 0;
    int seg = w * 2048;
    for (int base = 0; base < 2048; base += 64) {
        int j = seg + base + lane;
        float dx = __fsub_rn(pb[j * 3 + 0], qx);
        float dy = __fsub_rn(pb[j * 3 + 1], qy);
        float dz = __fsub_rn(pb[j * 3 + 2], qz);
        float d2 = __fadd_rn(__fadd_rn(__fmul_rn(dx, dx), __fmul_rn(dy, dy)),
                             __fmul_rn(dz, dz));
        bool hit = d2 < R2;
        u64 mask = __ballot(hit);
        if (hit) {
            int pos = cnt + __popcll(mask & ((1ull << lane) - 1ull));
            if (pos < KS) swidx[w][pos] = j;
        }
        cnt += __popcll(mask);
        if (cnt >= KS) break;
    }
    if (lane == 0) scnt[w] = cnt < KS ? cnt : KS;
    __syncthreads();
    int c0s = scnt[0], c1s = scnt[1], c2s = scnt[2], c3s = scnt[3];
    int st1 = c0s, st2 = c0s + c1s, st3 = c0s + c1s + c2s;
    int total = c0s + c1s + c2s + c3s; if (total > KS) total = KS;
    if (total < 1) total = 1;
    if (t < 128) {
        int ww = t >> 5, l = t & 31;
        int stw = (ww == 0) ? 0 : (ww == 1) ? st1 : (ww == 2) ? st2 : st3;
        int cw  = (ww == 0) ? c0s : (ww == 1) ? c1s : (ww == 2) ? c2s : c3s;
        int gp = stw + l;
        if (l < cw && gp < KS) nb[gp] = swidx[ww][l];
    }
    __syncthreads();
    if (t < KS) {
        int jk = nb[t < total ? t : 0] & (NPTS - 1);
        nbp[t] = jk;
        float dx = pb[jk * 3 + 0] - qx;
        float dy = pb[jk * 3 + 1] - qy;
        float dz = pb[jk * 3 + 2] - qz;
        float nr = fmaxf(sqrtf(dx * dx + dy * dy + dz * dz), 1e-12f);
        sdx[t] = dx / nr; sdy[t] = dy / nr; sdz[t] = dz / nr;
    }
    if (t >= 128) {
        lfi[t - 128] = f[((size_t)b * CIN + (t - 128)) * NPTS + i0];
    }
    __syncthreads();
    if (t < ND) {
        float ax = dirv[t * 3], ay = dirv[t * 3 + 1], az = dirv[t * 3 + 2];
        float n = fmaxf(sqrtf(ax * ax + ay * ay + az * az), 1e-12f);
        float vx = ax / n, vy = ay / n, vz = az / n;
        float tm = -1e30f;
#pragma unroll
        for (int k = 0; k < KS; ++k)
            tm = fmaxf(tm, vx * sdx[k] + vy * sdy[k] + vz * sdz[k]);
        ltm[t] = tm;
    }
    __syncthreads();

    int c = t;
    const float* f1b = f1t + (size_t)bl * NPTS * CO + c;
    float mx = -1e30f;
#pragma unroll 8
    for (int k = 0; k < KS; ++k) {
        mx = fmaxf(mx, f1b[(size_t)nbp[k] * CO]);
    }
    float sc1 = bn1_g[c] / sqrtf(bn1_v[c] + 1e-5f);
    float o1 = (mx - bn1_m[c]) * sc1 + bn1_b[c];

    float idv = skip_b[c];
    {
        const float4* sr = (const float4*)(skip_w + (size_t)c * CIN);
#pragma unroll 8
        for (int r = 0; r < 32; ++r) {
            float4 v = sr[r];
            idv = fmaf(v.x, lfi[r*4+0], fmaf(v.y, lfi[r*4+1],
                  fmaf(v.z, lfi[r*4+2], fmaf(v.w, lfi[r*4+3], idv))));
        }
    }
    {
        int hc = c & (HALF - 1);
        const float4* d1 = (const float4*)(de_w1 + (size_t)hc * ND);
        float a = 0.0f;
#pragma unroll
        for (int r = 0; r < 8; ++r) {
            float4 v = d1[r];
            a = fmaf(v.x, ltm[r*4+0], fmaf(v.y, ltm[r*4+1],
                fmaf(v.z, ltm[r*4+2], fmaf(v.w, ltm[r*4+3], a))));
        }
        float dsc = de_g[hc] / sqrtf(de_v[hc] + 1e-5f);
        float xb = (a - de_m[hc]) * dsc + de_bb[hc];
        float hv = 0.5f * xb * (1.0f + erff(xb * 0.70710678118654752440f));
        if (c < HALF) lh[c] = hv;
    }
    __syncthreads();
    float pe = de_b2[c];
    {
        const float4* d2p = (const float4*)(de_w2 + (size_t)c * HALF);
#pragma unroll 8
        for (int r = 0; r < 32; ++r) {
            float4 v = d2p[r];
            pe = fmaf(v.x, lh[r*4+0], fmaf(v.y, lh[r*4+1],
                 fmaf(v.z, lh[r*4+2], fmaf(v.w, lh[r*4+3], pe))));
        }
    }
    out_f[((size_t)b * CO + c) * MPTS + m] = o1 + pe + idv;
}

// ------------- fused fallback if ws too small ----------------------------------
__global__ __launch_bounds__(256) void k_featz_fused(
    const float* __restrict__ p, const float* __restrict__ f,
    const float* __restrict__ conv1_w, const float* __restrict__ conv1_b,
    const float* __restrict__ skip_w,  const float* __restrict__ skip_b,
    const float* __restrict__ bn1_g, const float* __restrict__ bn1_b,
    const float* __restrict__ bn1_m, const float* __restrict__ bn1_v,
    const float* __restrict__ dirv,  const float* __restrict__ de_w1,
    const float* __restrict__ de_g,  const float* __restrict__ de_bb,
    const float* __restrict__ de_m,  const float* __restrict__ de_v,
    const float* __restrict__ de_w2, const float* __restrict__ de_b2,
    const int* __restrict__ idx,     float* __restrict__ out_f) {
    __shared__ __align__(16) float fg[KS * CIN];
    __shared__ float sdx[KS], sdy[KS], sdz[KS];
    __shared__ float ltm[ND], lfi[CIN], lh[HALF];
    __shared__ int swidx[4][KS];
    __shared__ int scnt[4];
    __shared__ int nb[KS], nbp[KS];

    int q = blockIdx.x;
    int b = q >> 11;
    int m = q & (MPTS - 1);
    int t = threadIdx.x, lane = t & 63, w = t >> 6;
    const float* pb = p + (size_t)b * NPTS * 3;
    int i0 = idx[q] & (NPTS - 1);
    float qx = pb[i0 * 3 + 0], qy = pb[i0 * 3 + 1], qz = pb[i0 * 3 + 2];
    const float R2 = 0.1f * 0.1f;
    int cnt = 0;
    int seg = w * 2048;
    for (int base = 0; base < 2048; base += 64) {
        int j = seg + base + lane;
        float dx = __fsub_rn(pb[j * 3 + 0], qx);
        float dy = __fsub_rn(pb[j * 3 + 1], qy);
        float dz = __fsub_rn(pb[j * 3 + 2], qz);
        float d2 = __fadd_rn(__fadd_rn(__fmul_rn(dx, dx), __fmul_rn(dy, dy)),
                             __fmul_rn(dz, dz));
        bool hit = d2 < R2;
        u64 mask = __ballot(hit);
        if (hit) {
            int pos = cnt + __popcll(mask & ((1ull << lane) - 1ull));
            if (pos < KS) swidx[w][pos] = j;
        }
        cnt += __popcll(mask);
        if (cnt >= KS) break;
    }
    if (lane == 0) scnt[w] = cnt < KS ? cnt : KS;
    __syncthreads();
    int c0s = scnt[0], c1s = scnt[1], c2s = scnt[2], c3s = scnt[3];
    int st1 = c0s, st2 = c0s + c1s, st3 = c0s + c1s + c2s;
    int total = c0s + c1s + c2s + c3s; if (total > KS) total = KS;
    if (total < 1) total = 1;
    if (t < 128) {
        int ww = t >> 5, l = t & 31;
        int stw = (ww == 0) ? 0 : (ww == 1) ? st1 : (ww == 2) ? st2 : st3;
        int cw  = (ww == 0) ? c0s : (ww == 1) ? c1s : (ww == 2) ? c2s : c3s;
        int gp = stw + l;
        if (l < cw && gp < KS) nb[gp] = swidx[ww][l];
    }
    __syncthreads();
    if (t < KS) {
        int jk = nb[t < total ? t : 0] & (NPTS - 1);
        nbp[t] = jk;
        float dx = pb[jk * 3 + 0] - qx;
        float dy = pb[jk * 3 + 1] - qy;
        float dz = pb[jk * 3 + 2] - qz;
        float nr = fmaxf(sqrtf(dx * dx + dy * dy + dz * dz), 1e-12f);
        sdx[t] = dx / nr; sdy[t] = dy / nr; sdz[t] = dz / nr;
    }
    if (t >= 128) lfi[t - 128] = f[((size_t)b * CIN + (t - 128)) * NPTS + i0];
    __syncthreads();
    if (t < ND) {
        float ax = dirv[t * 3], ay = dirv[t * 3 + 1], az = dirv[t * 3 + 2];
        float n = fmaxf(sqrtf(ax * ax + ay * ay + az * az), 1e-12f);
        float vx = ax / n, vy = ay / n, vz = az / n;
        float tm = -1e30f;
#pragma unroll
        for (int k = 0; k < KS; ++k)
            tm = fmaxf(tm, vx * sdx[k] + vy * sdy[k] + vz * sdz[k]);
        ltm[t] = tm;
    }
    for (int e = t; e < KS * CIN; e += 256) {
        int k = e >> 7, i = e & 127;
        fg[k * CIN + i] = f[((size_t)b * CIN + i) * NPTS + nbp[k]];
    }
    __syncthreads();
    int c = t;
    float acc[KS];
#pragma unroll
    for (int k = 0; k < KS; ++k) acc[k] = 0.0f;
    const float4* w4 = (const float4*)(conv1_w + (size_t)c * CIN);
    const float4* fg4 = (const float4*)fg;
    for (int i4 = 0; i4 < 32; ++i4) {
        float4 wv = w4[i4];
#pragma unroll 8
        for (int k = 0; k < KS; ++k) {
            float4 g = fg4[k * 32 + i4];
            acc[k] = fmaf(wv.x, g.x, fmaf(wv.y, g.y,
                     fmaf(wv.z, g.z, fmaf(wv.w, g.w, acc[k]))));
        }
    }
    float bias = conv1_b[c];
    float mx = -1e30f;
#pragma unroll
    for (int k = 0; k < KS; ++k) mx = fmaxf(mx, acc[k] + bias);
    float sc1 = bn1_g[c] / sqrtf(bn1_v[c] + 1e-5f);
    float o1 = (mx - bn1_m[c]) * sc1 + bn1_b[c];
    float idv = skip_b[c];
    {
        const float4* sr = (const float4*)(skip_w + (size_t)c * CIN);
#pragma unroll 8
        for (int r = 0; r < 32; ++r) {
            float4 v = sr[r];
            idv = fmaf(v.x, lfi[r*4+0], fmaf(v.y, lfi[r*4+1],
                  fmaf(v.z, lfi[r*4+2], fmaf(v.w, lfi[r*4+3], idv))));
        }
    }
    {
        int hc = c & (HALF - 1);
        const float4* d1 = (const float4*)(de_w1 + (size_t)hc * ND);
        float a = 0.0f;
#pragma unroll
        for (int r = 0; r < 8; ++r) {
            float4 v = d1[r];
            a = fmaf(v.x, ltm[r*4+0], fmaf(v.y, ltm[r*4+1],
                fmaf(v.z, ltm[r*4+2], fmaf(v.w, ltm[r*4+3], a))));
        }
        float dsc = de_g[hc] / sqrtf(de_v[hc] + 1e-5f);
        float xb = (a - de_m[hc]) * dsc + de_bb[hc];
        float hv = 0.5f * xb * (1.0f + erff(xb * 0.70710678118654752440f));
        if (c < HALF) lh[c] = hv;
    }
    __syncthreads();
    float pe = de_b2[c];
    {
        const float4* d2p = (const float4*)(de_w2 + (size_t)c * HALF);
#pragma unroll 8
        for (int r = 0; r < 32; ++r) {
            float4 v = d2p[r];
            pe = fmaf(v.x, lh[r*4+0], fmaf(v.y, lh[r*4+1],
                 fmaf(v.z, lh[r*4+2], fmaf(v.w, lh[r*4+3], pe))));
        }
    }
    out_f[((size_t)b * CO + c) * MPTS + m] = o1 + pe + idv;
}

extern "C" void kernel_launch(void* const* d_in, const int* in_sizes, int n_in,
                              void* d_out, int out_size, void* d_ws, size_t ws_size,
                              hipStream_t stream) {
    const float* p       = (const float*)d_in[0];
    const float* f       = (const float*)d_in[1];
    const float* conv1_w = (const float*)d_in[2];
    const float* conv1_b = (const float*)d_in[3];
    const float* skip_w  = (const float*)d_in[4];
    const float* skip_b  = (const float*)d_in[5];
    const float* bn1_g   = (const float*)d_in[6];
    const float* bn1_b   = (const float*)d_in[7];
    const float* bn1_m   = (const float*)d_in[8];
    const float* bn1_v   = (const float*)d_in[9];
    const float* dirv    = (const float*)d_in[10];
    const float* de_w1   = (const float*)d_in[11];
    const float* de_g    = (const float*)d_in[12];
    const float* de_bb   = (const float*)d_in[13];
    const float* de_m    = (const float*)d_in[14];
    const float* de_v    = (const float*)d_in[15];
    const float* de_w2   = (const float*)d_in[16];
    const float* de_b2   = (const float*)d_in[17];

    float* out_newp = (float*)d_out;
    float* out_f    = (float*)d_out + (size_t)BATCH * MPTS * 3;
    int*   idx      = (int*)d_ws;                         // 32 KB
    float* f1t      = (float*)((char*)d_ws + 32768);

    size_t f1_one  = (size_t)NPTS * CO * 4;               // 8 MB per batch
    size_t need_full = 32768 + 4 * f1_one;
    size_t need_one  = 32768 + f1_one;
    int mode = (ws_size >= need_full) ? 2 : (ws_size >= need_one) ? 1 : 0;

    if (mode == 2) {
        // FPS on 4 blocks + f1 on 1024 blocks, concurrently in one kernel
        k_fps_f1<<<dim3(4 + 1024), dim3(512), 0, stream>>>(
            p, f, conv1_w, conv1_b, out_newp, idx, f1t);
        k_feat<<<dim3(4 * MPTS), dim3(256), 0, stream>>>(
            p, f, f1t, skip_w, skip_b, bn1_g, bn1_b, bn1_m, bn1_v,
            dirv, de_w1, de_g, de_bb, de_m, de_v, de_w2, de_b2, idx, out_f, 0);
    } else if (mode == 1) {
        k_fps_f1<<<dim3(4), dim3(512), 0, stream>>>(
            p, f, conv1_w, conv1_b, out_newp, idx, nullptr);
        for (int b0 = 0; b0 < BATCH; ++b0) {
            k_f1  <<<dim3(512),  dim3(256), 0, stream>>>(f, conv1_w, conv1_b, f1t, b0);
            k_feat<<<dim3(MPTS), dim3(256), 0, stream>>>(
                p, f, f1t, skip_w, skip_b, bn1_g, bn1_b, bn1_m, bn1_v,
                dirv, de_w1, de_g, de_bb, de_m, de_v, de_w2, de_b2, idx, out_f, b0);
        }
    } else {
        k_fps_f1<<<dim3(4), dim3(512), 0, stream>>>(
            p, f, conv1_w, conv1_b, out_newp, idx, nullptr);
        k_featz_fused<<<dim3(BATCH * MPTS), dim3(256), 0, stream>>>(
            p, f, conv1_w, conv1_b, skip_w, skip_b, bn1_g, bn1_b, bn1_m, bn1_v,
            dirv, de_w1, de_g, de_bb, de_m, de_v, de_w2, de_b2, idx, out_f);
    }
}